// Round 1
// baseline (814.954 us; speedup 1.0000x reference)
//
#include <hip/hip_runtime.h>
#include <float.h>

#define NN 50000
#define NE 800000
#define NG 64
#define CAP 64

// ---------- order-preserving float <-> uint for atomic max ----------
__device__ __forceinline__ unsigned f2mono(float f) {
  unsigned b = __float_as_uint(f);
  return (b & 0x80000000u) ? ~b : (b | 0x80000000u);
}
__device__ __forceinline__ float mono2f(unsigned u) {
  unsigned b = (u & 0x80000000u) ? (u & 0x7fffffffu) : ~u;
  return __uint_as_float(b);
}

// ---------- degree count + ELL adjacency fill (by dst) ----------
__global__ void k_count(const int* __restrict__ src, const int* __restrict__ dst,
                        int* __restrict__ cnt, int* __restrict__ col) {
  int e = blockIdx.x * blockDim.x + threadIdx.x;
  if (e >= NE) return;
  int d = dst[e];
  int s = src[e];
  if ((unsigned)d >= NN || (unsigned)s >= NN) return;  // dtype-mismatch safety
  int pos = atomicAdd(&cnt[d], 1);
  if (pos < CAP) col[d * CAP + pos] = s;
}

__global__ void k_dinv(const int* __restrict__ cnt, float* __restrict__ dinv) {
  int v = blockIdx.x * blockDim.x + threadIdx.x;
  if (v < NN) dinv[v] = rsqrtf((float)cnt[v] + 1.0f);  // +1 self-loop
}

// ---------- aggregation F=9 (thread per node) ----------
__global__ void k_agg9(const float* __restrict__ x, float* __restrict__ out,
                       const int* __restrict__ cnt, const int* __restrict__ col,
                       const float* __restrict__ dinv) {
  int v = blockIdx.x * blockDim.x + threadIdx.x;
  if (v >= NN) return;
  float di = dinv[v];
  float acc[9];
#pragma unroll
  for (int i = 0; i < 9; ++i) acc[i] = x[v * 9 + i] * di;
  int c = cnt[v]; if (c > CAP) c = CAP;
  const int* cl = col + v * CAP;
  for (int j = 0; j < c; ++j) {
    int u = cl[j];
    float du = dinv[u];
#pragma unroll
    for (int i = 0; i < 9; ++i) acc[i] += x[u * 9 + i] * du;
  }
#pragma unroll
  for (int i = 0; i < 9; ++i) out[v * 9 + i] = acc[i] * di;
}

// ---------- GEMM K=9 -> 128, + bias + relu ----------
__global__ __launch_bounds__(256) void k_gemm9(const float* __restrict__ in,
                                               const float* __restrict__ W,
                                               const float* __restrict__ bias,
                                               float* __restrict__ out) {
  __shared__ float sW[9 * 128];
  __shared__ float sb[128];
  int t = threadIdx.x;
  if (t < 128) sb[t] = bias[t];
  for (int i = t; i < 9 * 128; i += 256) sW[i] = W[i];
  __syncthreads();
  int r = blockIdx.x * 2 + (t >> 7);
  int c = t & 127;
  if (r >= NN) return;
  float acc = sb[c];
#pragma unroll
  for (int i = 0; i < 9; ++i) acc += in[r * 9 + i] * sW[i * 128 + c];
  out[r * 128 + c] = fmaxf(acc, 0.0f);
}

// ---------- aggregation F=128 (wave per node, float2 per lane) ----------
__global__ __launch_bounds__(256) void k_agg128(const float2* __restrict__ h,
                                                float2* __restrict__ out,
                                                const int* __restrict__ cnt,
                                                const int* __restrict__ col,
                                                const float* __restrict__ dinv) {
  int w = (blockIdx.x * 256 + threadIdx.x) >> 6;
  int lane = threadIdx.x & 63;
  if (w >= NN) return;
  float di = dinv[w];
  float2 s = h[(size_t)w * 64 + lane];
  float ax = s.x * di, ay = s.y * di;
  int c = cnt[w]; if (c > CAP) c = CAP;
  const int* cl = col + w * CAP;
  for (int j = 0; j < c; ++j) {
    int u = cl[j];
    float du = dinv[u];
    float2 tv = h[(size_t)u * 64 + lane];
    ax += tv.x * du; ay += tv.y * du;
  }
  out[(size_t)w * 64 + lane] = make_float2(ax * di, ay * di);
}

// ---------- aggregation F=256 (wave per node, float4 per lane) ----------
__global__ __launch_bounds__(256) void k_agg256(const float4* __restrict__ h,
                                                float4* __restrict__ out,
                                                const int* __restrict__ cnt,
                                                const int* __restrict__ col,
                                                const float* __restrict__ dinv) {
  int w = (blockIdx.x * 256 + threadIdx.x) >> 6;
  int lane = threadIdx.x & 63;
  if (w >= NN) return;
  float di = dinv[w];
  float4 s = h[(size_t)w * 64 + lane];
  float ax = s.x * di, ay = s.y * di, az = s.z * di, aw = s.w * di;
  int c = cnt[w]; if (c > CAP) c = CAP;
  const int* cl = col + w * CAP;
  for (int j = 0; j < c; ++j) {
    int u = cl[j];
    float du = dinv[u];
    float4 tv = h[(size_t)u * 64 + lane];
    ax += tv.x * du; ay += tv.y * du; az += tv.z * du; aw += tv.w * du;
  }
  out[(size_t)w * 64 + lane] = make_float4(ax * di, ay * di, az * di, aw * di);
}

// ---------- main fp32 GEMM: C[MxNc] = A[MxK] @ W[KxNc] + bias (+relu) ----------
#define GBM 128
#define GBN 128
#define GBK 16
__global__ __launch_bounds__(256) void k_gemm(const float* __restrict__ Ain,
                                              const float* __restrict__ Bw,
                                              const float* __restrict__ bias,
                                              float* __restrict__ Cout,
                                              int M, int K, int Nc, int relu) {
  __shared__ float As[GBK][GBM + 4];  // A stored transposed: As[k][m]
  __shared__ float Bs[GBK][GBN + 4];
  int t = threadIdx.x;
  int trow = t >> 4, tcol = t & 15;
  int rowBase = blockIdx.x * GBM;
  int colBase = blockIdx.y * GBN;
  float acc[8][8];
#pragma unroll
  for (int i = 0; i < 8; ++i)
#pragma unroll
    for (int j = 0; j < 8; ++j) acc[i][j] = 0.0f;

  int ntiles = K / GBK;
  for (int kt = 0; kt < ntiles; ++kt) {
    int k0 = kt * GBK;
#pragma unroll
    for (int l = 0; l < 2; ++l) {          // A tile: 128 rows x 16 k
      int i = t + 256 * l;                 // float4 index 0..511
      int m = i >> 2;
      int kq = (i & 3) << 2;
      int gr = rowBase + m;
      float4 v = make_float4(0.f, 0.f, 0.f, 0.f);
      if (gr < M) v = *(const float4*)(Ain + (size_t)gr * K + k0 + kq);
      As[kq + 0][m] = v.x; As[kq + 1][m] = v.y; As[kq + 2][m] = v.z; As[kq + 3][m] = v.w;
    }
#pragma unroll
    for (int l = 0; l < 2; ++l) {          // B tile: 16 k x 128 cols
      int i = t + 256 * l;
      int kk = i >> 5;
      int c4 = (i & 31) << 2;
      float4 v = *(const float4*)(Bw + (size_t)(k0 + kk) * Nc + colBase + c4);
      *(float4*)&Bs[kk][c4] = v;
    }
    __syncthreads();
#pragma unroll
    for (int kk = 0; kk < GBK; ++kk) {
      float a[8], b[8];
#pragma unroll
      for (int i = 0; i < 8; ++i) a[i] = As[kk][trow * 8 + i];
#pragma unroll
      for (int j = 0; j < 8; ++j) b[j] = Bs[kk][tcol * 8 + j];
#pragma unroll
      for (int i = 0; i < 8; ++i)
#pragma unroll
        for (int j = 0; j < 8; ++j) acc[i][j] += a[i] * b[j];
    }
    __syncthreads();
  }
#pragma unroll
  for (int i = 0; i < 8; ++i) {
    int gr = rowBase + trow * 8 + i;
    if (gr >= M) break;
#pragma unroll
    for (int j = 0; j < 8; ++j) {
      int gc = colBase + tcol * 8 + j;
      float v = acc[i][j] + bias[gc];
      if (relu) v = fmaxf(v, 0.0f);
      Cout[(size_t)gr * Nc + gc] = v;
    }
  }
}

// ---------- global max pool over sorted batch ----------
#define PCH 64
__global__ __launch_bounds__(256) void k_pool(const float* __restrict__ h,
                                              const int* __restrict__ batch,
                                              unsigned* __restrict__ g) {
  int t = threadIdx.x;
  int n0 = blockIdx.x * PCH;
  int n1 = n0 + PCH; if (n1 > NN) n1 = NN;
  if (n0 >= NN) return;
  int cur = batch[n0];
  float m = -FLT_MAX;
  for (int n = n0; n < n1; ++n) {
    int b = batch[n];
    if (b != cur) {
      if ((unsigned)cur < NG) atomicMax(&g[cur * 256 + t], f2mono(m));
      m = -FLT_MAX; cur = b;
    }
    m = fmaxf(m, h[(size_t)n * 256 + t]);
  }
  if ((unsigned)cur < NG) atomicMax(&g[cur * 256 + t], f2mono(m));
}

// ---------- dense head: 256 ->128 relu ->128 relu ->10, one block per graph ----------
__global__ __launch_bounds__(256) void k_head(const unsigned* __restrict__ g,
                                              const float* __restrict__ Wl2, const float* __restrict__ bl2,
                                              const float* __restrict__ Wl3, const float* __restrict__ bl3,
                                              const float* __restrict__ Wl, const float* __restrict__ bl,
                                              float* __restrict__ out) {
  __shared__ float s0[256];
  __shared__ float s1[128];
  __shared__ float s2[128];
  int b = blockIdx.x, t = threadIdx.x;
  s0[t] = mono2f(g[b * 256 + t]);
  __syncthreads();
  if (t < 128) {
    float acc = bl2[t];
    for (int k = 0; k < 256; ++k) acc += s0[k] * Wl2[k * 128 + t];
    s1[t] = fmaxf(acc, 0.0f);
  }
  __syncthreads();
  if (t < 128) {
    float acc = bl3[t];
    for (int k = 0; k < 128; ++k) acc += s1[k] * Wl3[k * 128 + t];
    s2[t] = fmaxf(acc, 0.0f);
  }
  __syncthreads();
  if (t < 10) {
    float acc = bl[t];
    for (int k = 0; k < 128; ++k) acc += s2[k] * Wl[k * 10 + t];
    out[b * 10 + t] = acc;
  }
}

extern "C" void kernel_launch(void* const* d_in, const int* in_sizes, int n_in,
                              void* d_out, int out_size, void* d_ws, size_t ws_size,
                              hipStream_t stream) {
  const float* x   = (const float*)d_in[0];
  const int* eidx  = (const int*)d_in[1];
  const int* batch = (const int*)d_in[2];
  const float* W1 = (const float*)d_in[3];   const float* b1 = (const float*)d_in[4];
  const float* W2 = (const float*)d_in[5];   const float* b2 = (const float*)d_in[6];
  const float* W3 = (const float*)d_in[7];   const float* b3 = (const float*)d_in[8];
  const float* W4 = (const float*)d_in[9];   const float* b4 = (const float*)d_in[10];
  const float* Wl2 = (const float*)d_in[11]; const float* bl2 = (const float*)d_in[12];
  const float* Wl3 = (const float*)d_in[13]; const float* bl3 = (const float*)d_in[14];
  const float* Wl  = (const float*)d_in[15]; const float* bl  = (const float*)d_in[16];
  float* out = (float*)d_out;

  // workspace carve: A,B ping-pong (N x 256 fp32 each), cnt, dinv, ELL col, pooled g
  float* A  = (float*)d_ws;                       // NN*256
  float* Bb = A + (size_t)NN * 256;               // NN*256
  int* cnt  = (int*)(Bb + (size_t)NN * 256);      // NN
  float* dinv = (float*)(cnt + NN);               // NN
  int* col  = (int*)(dinv + NN);                  // NN*CAP
  unsigned* g = (unsigned*)(col + (size_t)NN * CAP);  // NG*256

  const int* src = eidx;          // edge_index[0]
  const int* dst = eidx + NE;     // edge_index[1]

  hipMemsetAsync(cnt, 0, NN * sizeof(int), stream);
  hipMemsetAsync(g, 0, NG * 256 * sizeof(unsigned), stream);

  k_count<<<(NE + 255) / 256, 256, 0, stream>>>(src, dst, cnt, col);
  k_dinv<<<(NN + 255) / 256, 256, 0, stream>>>(cnt, dinv);

  // layer 1: aggregate 9-dim, then 9->128 GEMM (+relu)      [ (A~h)W == A~(hW) ]
  k_agg9<<<(NN + 255) / 256, 256, 0, stream>>>(x, Bb, cnt, col, dinv);
  k_gemm9<<<NN / 2, 256, 0, stream>>>(Bb, W1, b1, A);

  // layer 2: aggregate 128-dim, then 128->256 GEMM (+relu)
  k_agg128<<<(NN + 3) / 4, 256, 0, stream>>>((const float2*)A, (float2*)Bb, cnt, col, dinv);
  {
    dim3 gr((NN + GBM - 1) / GBM, 256 / GBN);
    k_gemm<<<gr, 256, 0, stream>>>(Bb, W2, b2, A, NN, 128, 256, 1);
  }

  // layer 3: aggregate 256-dim, then 256->256 GEMM (+relu)
  k_agg256<<<(NN + 3) / 4, 256, 0, stream>>>((const float4*)A, (float4*)Bb, cnt, col, dinv);
  {
    dim3 gr((NN + GBM - 1) / GBM, 256 / GBN);
    k_gemm<<<gr, 256, 0, stream>>>(Bb, W3, b3, A, NN, 256, 256, 1);
  }

  // layer 4: aggregate 256-dim, then 256->256 GEMM (no relu)
  k_agg256<<<(NN + 3) / 4, 256, 0, stream>>>((const float4*)A, (float4*)Bb, cnt, col, dinv);
  {
    dim3 gr((NN + GBM - 1) / GBM, 256 / GBN);
    k_gemm<<<gr, 256, 0, stream>>>(Bb, W4, b4, A, NN, 256, 256, 0);
  }

  // pool + head
  k_pool<<<(NN + PCH - 1) / PCH, 256, 0, stream>>>(A, batch, g);
  k_head<<<NG, 256, 0, stream>>>(g, Wl2, bl2, Wl3, bl3, Wl, bl, out);
}

// Round 2
// 751.054 us; speedup vs baseline: 1.0851x; 1.0851x over previous
//
#include <hip/hip_runtime.h>
#include <float.h>

#define NN 50000
#define NE 800000
#define NG 64
#define CAP 64

typedef __attribute__((ext_vector_type(8))) short bf16x8;
typedef __attribute__((ext_vector_type(4))) float f32x4;

// ---------- helpers ----------
__device__ __forceinline__ unsigned f2mono(float f) {
  unsigned b = __float_as_uint(f);
  return (b & 0x80000000u) ? ~b : (b | 0x80000000u);
}
__device__ __forceinline__ float mono2f(unsigned u) {
  unsigned b = (u & 0x80000000u) ? (u & 0x7fffffffu) : ~u;
  return __uint_as_float(b);
}
// round-to-nearest-even fp32 -> bf16 bits
__device__ __forceinline__ unsigned short bf16rn(float f) {
  unsigned u = __float_as_uint(f);
  unsigned r = u + 0x7FFFu + ((u >> 16) & 1u);
  return (unsigned short)(r >> 16);
}
__device__ __forceinline__ float bf2f(unsigned short h) {
  return __uint_as_float(((unsigned)h) << 16);
}
__device__ __forceinline__ void split2(float a, unsigned short* hi, unsigned short* lo) {
  unsigned short h = bf16rn(a);
  *hi = h;
  *lo = bf16rn(a - bf2f(h));
}

// ---------- degree count + ELL adjacency fill (by dst) ----------
__global__ void k_count(const int* __restrict__ src, const int* __restrict__ dst,
                        int* __restrict__ cnt, int* __restrict__ col) {
  int e = blockIdx.x * blockDim.x + threadIdx.x;
  if (e >= NE) return;
  int d = dst[e];
  int s = src[e];
  if ((unsigned)d >= NN || (unsigned)s >= NN) return;
  int pos = atomicAdd(&cnt[d], 1);
  if (pos < CAP) col[d * CAP + pos] = s;
}

__global__ void k_dinv(const int* __restrict__ cnt, float* __restrict__ dinv) {
  int v = blockIdx.x * blockDim.x + threadIdx.x;
  if (v < NN) dinv[v] = rsqrtf((float)cnt[v] + 1.0f);
}

// ---------- weight split + transpose: W[K][Nc] fp32 -> Wt_hi/lo[Nc][K] bf16 ----------
__global__ void k_splitw(const float* __restrict__ W, unsigned short* __restrict__ Whi,
                         unsigned short* __restrict__ Wlo, int K, int Nc) {
  int i = blockIdx.x * blockDim.x + threadIdx.x;
  if (i >= K * Nc) return;
  int k = i / Nc, n = i - k * Nc;
  float w = W[i];
  unsigned short h, l;
  split2(w, &h, &l);
  Whi[(size_t)n * K + k] = h;
  Wlo[(size_t)n * K + k] = l;
}

// ---------- aggregation F=9 (thread per node) ----------
__global__ void k_agg9(const float* __restrict__ x, float* __restrict__ out,
                       const int* __restrict__ cnt, const int* __restrict__ col,
                       const float* __restrict__ dinv) {
  int v = blockIdx.x * blockDim.x + threadIdx.x;
  if (v >= NN) return;
  float di = dinv[v];
  float acc[9];
#pragma unroll
  for (int i = 0; i < 9; ++i) acc[i] = x[v * 9 + i] * di;
  int c = cnt[v]; if (c > CAP) c = CAP;
  const int* cl = col + v * CAP;
  for (int j = 0; j < c; ++j) {
    int u = cl[j];
    float du = dinv[u];
#pragma unroll
    for (int i = 0; i < 9; ++i) acc[i] += x[u * 9 + i] * du;
  }
#pragma unroll
  for (int i = 0; i < 9; ++i) out[v * 9 + i] = acc[i] * di;
}

// ---------- GEMM K=9 -> 128, + bias + relu (fp32 vector, tiny K) ----------
__global__ __launch_bounds__(256) void k_gemm9(const float* __restrict__ in,
                                               const float* __restrict__ W,
                                               const float* __restrict__ bias,
                                               float* __restrict__ out) {
  __shared__ float sW[9 * 128];
  __shared__ float sb[128];
  int t = threadIdx.x;
  if (t < 128) sb[t] = bias[t];
  for (int i = t; i < 9 * 128; i += 256) sW[i] = W[i];
  __syncthreads();
  int r = blockIdx.x * 2 + (t >> 7);
  int c = t & 127;
  if (r >= NN) return;
  float acc = sb[c];
#pragma unroll
  for (int i = 0; i < 9; ++i) acc += in[r * 9 + i] * sW[i * 128 + c];
  out[r * 128 + c] = fmaxf(acc, 0.0f);
}

// ---------- aggregation F=128 (wave/node), emits split bf16 ----------
__global__ __launch_bounds__(256) void k_agg128(const float2* __restrict__ h,
                                                unsigned short* __restrict__ Ahi,
                                                unsigned short* __restrict__ Alo,
                                                const int* __restrict__ cnt,
                                                const int* __restrict__ col,
                                                const float* __restrict__ dinv) {
  int w = (blockIdx.x * 256 + threadIdx.x) >> 6;
  int lane = threadIdx.x & 63;
  if (w >= NN) return;
  float di = dinv[w];
  float2 s = h[(size_t)w * 64 + lane];
  float ax = s.x * di, ay = s.y * di;
  int c = cnt[w]; if (c > CAP) c = CAP;
  const int* cl = col + w * CAP;
  for (int j = 0; j < c; ++j) {
    int u = cl[j];
    float du = dinv[u];
    float2 tv = h[(size_t)u * 64 + lane];
    ax += tv.x * du; ay += tv.y * du;
  }
  ax *= di; ay *= di;
  ushort2 hv, lv;
  split2(ax, &hv.x, &lv.x);
  split2(ay, &hv.y, &lv.y);
  *(ushort2*)(Ahi + (size_t)w * 128 + 2 * lane) = hv;
  *(ushort2*)(Alo + (size_t)w * 128 + 2 * lane) = lv;
}

// ---------- aggregation F=256 (wave/node), emits split bf16 ----------
__global__ __launch_bounds__(256) void k_agg256(const float4* __restrict__ h,
                                                unsigned short* __restrict__ Ahi,
                                                unsigned short* __restrict__ Alo,
                                                const int* __restrict__ cnt,
                                                const int* __restrict__ col,
                                                const float* __restrict__ dinv) {
  int w = (blockIdx.x * 256 + threadIdx.x) >> 6;
  int lane = threadIdx.x & 63;
  if (w >= NN) return;
  float di = dinv[w];
  float4 s = h[(size_t)w * 64 + lane];
  float ax = s.x * di, ay = s.y * di, az = s.z * di, aw = s.w * di;
  int c = cnt[w]; if (c > CAP) c = CAP;
  const int* cl = col + w * CAP;
  for (int j = 0; j < c; ++j) {
    int u = cl[j];
    float du = dinv[u];
    float4 tv = h[(size_t)u * 64 + lane];
    ax += tv.x * du; ay += tv.y * du; az += tv.z * du; aw += tv.w * du;
  }
  ax *= di; ay *= di; az *= di; aw *= di;
  ushort4 hv, lv;
  split2(ax, &hv.x, &lv.x);
  split2(ay, &hv.y, &lv.y);
  split2(az, &hv.z, &lv.z);
  split2(aw, &hv.w, &lv.w);
  *(ushort4*)(Ahi + (size_t)w * 256 + 4 * lane) = hv;
  *(ushort4*)(Alo + (size_t)w * 256 + 4 * lane) = lv;
}

// ---------- MFMA bf16x3-split GEMM: C[M][Nc] = A[M][K] @ Wt[Nc][K]^T + bias ----------
// block = 256 thr = 4 waves (2x2), block tile 128x128, wave tile 64x64 = 4x4 frags 16x16
__global__ __launch_bounds__(256) void k_mm(const unsigned short* __restrict__ Ahi,
                                            const unsigned short* __restrict__ Alo,
                                            const unsigned short* __restrict__ Bhi,
                                            const unsigned short* __restrict__ Blo,
                                            const float* __restrict__ bias,
                                            float* __restrict__ C,
                                            int M, int K, int Nc, int relu) {
  int t = threadIdx.x;
  int wave = t >> 6, lane = t & 63;
  int wm = wave & 1, wn = wave >> 1;
  int rowBase = blockIdx.x * 128 + wm * 64;
  int colBase = blockIdx.y * 128 + wn * 64;
  int lm = lane & 15;            // m (A) / n (B) within a 16-frag
  int lk = (lane >> 4) * 8;      // k offset within 32

  f32x4 acc[4][4];
#pragma unroll
  for (int i = 0; i < 4; ++i)
#pragma unroll
    for (int j = 0; j < 4; ++j) acc[i][j] = (f32x4){0.f, 0.f, 0.f, 0.f};

  const bf16x8 zf = {};

  for (int k0 = 0; k0 < K; k0 += 32) {
    bf16x8 ah[4], al[4], bh[4], bl[4];
#pragma unroll
    for (int mi = 0; mi < 4; ++mi) {
      int r = rowBase + mi * 16 + lm;
      if (r < M) {
        size_t off = (size_t)r * K + k0 + lk;
        ah[mi] = *(const bf16x8*)(Ahi + off);
        al[mi] = *(const bf16x8*)(Alo + off);
      } else { ah[mi] = zf; al[mi] = zf; }
    }
#pragma unroll
    for (int ni = 0; ni < 4; ++ni) {
      int c = colBase + ni * 16 + lm;
      size_t off = (size_t)c * K + k0 + lk;
      bh[ni] = *(const bf16x8*)(Bhi + off);
      bl[ni] = *(const bf16x8*)(Blo + off);
    }
#pragma unroll
    for (int mi = 0; mi < 4; ++mi)
#pragma unroll
      for (int ni = 0; ni < 4; ++ni) {
        acc[mi][ni] = __builtin_amdgcn_mfma_f32_16x16x32_bf16(ah[mi], bh[ni], acc[mi][ni], 0, 0, 0);
        acc[mi][ni] = __builtin_amdgcn_mfma_f32_16x16x32_bf16(ah[mi], bl[ni], acc[mi][ni], 0, 0, 0);
        acc[mi][ni] = __builtin_amdgcn_mfma_f32_16x16x32_bf16(al[mi], bh[ni], acc[mi][ni], 0, 0, 0);
      }
  }

  // C/D layout: n = lane&15, m = (lane>>4)*4 + reg
  int rowOff = (lane >> 4) * 4;
#pragma unroll
  for (int mi = 0; mi < 4; ++mi) {
#pragma unroll
    for (int ni = 0; ni < 4; ++ni) {
      int gc = colBase + ni * 16 + lm;
      float bsv = bias[gc];
#pragma unroll
      for (int r = 0; r < 4; ++r) {
        int gr = rowBase + mi * 16 + rowOff + r;
        if (gr < M) {
          float v = acc[mi][ni][r] + bsv;
          if (relu) v = fmaxf(v, 0.0f);
          C[(size_t)gr * Nc + gc] = v;
        }
      }
    }
  }
}

// ---------- global max pool over sorted batch ----------
#define PCH 64
__global__ __launch_bounds__(256) void k_pool(const float* __restrict__ h,
                                              const int* __restrict__ batch,
                                              unsigned* __restrict__ g) {
  int t = threadIdx.x;
  int n0 = blockIdx.x * PCH;
  int n1 = n0 + PCH; if (n1 > NN) n1 = NN;
  if (n0 >= NN) return;
  int cur = batch[n0];
  float m = -FLT_MAX;
  for (int n = n0; n < n1; ++n) {
    int b = batch[n];
    if (b != cur) {
      if ((unsigned)cur < NG) atomicMax(&g[cur * 256 + t], f2mono(m));
      m = -FLT_MAX; cur = b;
    }
    m = fmaxf(m, h[(size_t)n * 256 + t]);
  }
  if ((unsigned)cur < NG) atomicMax(&g[cur * 256 + t], f2mono(m));
}

// ---------- dense head ----------
__global__ __launch_bounds__(256) void k_head(const unsigned* __restrict__ g,
                                              const float* __restrict__ Wl2, const float* __restrict__ bl2,
                                              const float* __restrict__ Wl3, const float* __restrict__ bl3,
                                              const float* __restrict__ Wl, const float* __restrict__ bl,
                                              float* __restrict__ out) {
  __shared__ float s0[256];
  __shared__ float s1[128];
  __shared__ float s2[128];
  int b = blockIdx.x, t = threadIdx.x;
  s0[t] = mono2f(g[b * 256 + t]);
  __syncthreads();
  if (t < 128) {
    float acc = bl2[t];
    for (int k = 0; k < 256; ++k) acc += s0[k] * Wl2[k * 128 + t];
    s1[t] = fmaxf(acc, 0.0f);
  }
  __syncthreads();
  if (t < 128) {
    float acc = bl3[t];
    for (int k = 0; k < 128; ++k) acc += s1[k] * Wl3[k * 128 + t];
    s2[t] = fmaxf(acc, 0.0f);
  }
  __syncthreads();
  if (t < 10) {
    float acc = bl[t];
    for (int k = 0; k < 128; ++k) acc += s2[k] * Wl[k * 10 + t];
    out[b * 10 + t] = acc;
  }
}

extern "C" void kernel_launch(void* const* d_in, const int* in_sizes, int n_in,
                              void* d_out, int out_size, void* d_ws, size_t ws_size,
                              hipStream_t stream) {
  const float* x   = (const float*)d_in[0];
  const int* eidx  = (const int*)d_in[1];
  const int* batch = (const int*)d_in[2];
  const float* W1 = (const float*)d_in[3];   const float* b1 = (const float*)d_in[4];
  const float* W2 = (const float*)d_in[5];   const float* b2 = (const float*)d_in[6];
  const float* W3 = (const float*)d_in[7];   const float* b3 = (const float*)d_in[8];
  const float* W4 = (const float*)d_in[9];   const float* b4 = (const float*)d_in[10];
  const float* Wl2 = (const float*)d_in[11]; const float* bl2 = (const float*)d_in[12];
  const float* Wl3 = (const float*)d_in[13]; const float* bl3 = (const float*)d_in[14];
  const float* Wl  = (const float*)d_in[15]; const float* bl  = (const float*)d_in[16];
  float* out = (float*)d_out;

  // ---- workspace carve ----
  float* h = (float*)d_ws;                                   // NN*256 fp32
  unsigned short* Ahi = (unsigned short*)(h + (size_t)NN * 256);   // NN*256 bf16
  unsigned short* Alo = Ahi + (size_t)NN * 256;                    // NN*256 bf16
  int* cnt  = (int*)(Alo + (size_t)NN * 256);                // NN
  float* dinv = (float*)(cnt + NN);                          // NN
  int* col  = (int*)(dinv + NN);                             // NN*CAP
  unsigned* g = (unsigned*)(col + (size_t)NN * CAP);         // NG*256
  unsigned short* W2hi = (unsigned short*)(g + NG * 256);    // 128*256
  unsigned short* W2lo = W2hi + 128 * 256;
  unsigned short* W3hi = W2lo + 128 * 256;                   // 256*256
  unsigned short* W3lo = W3hi + 256 * 256;
  unsigned short* W4hi = W3lo + 256 * 256;
  unsigned short* W4lo = W4hi + 256 * 256;
  float* agg9out = (float*)Ahi;  // NN*9 fp32 fits in Ahi region (used before Ahi is)

  const int* src = eidx;
  const int* dst = eidx + NE;

  hipMemsetAsync(cnt, 0, NN * sizeof(int), stream);
  hipMemsetAsync(g, 0, NG * 256 * sizeof(unsigned), stream);

  k_count<<<(NE + 255) / 256, 256, 0, stream>>>(src, dst, cnt, col);
  k_dinv<<<(NN + 255) / 256, 256, 0, stream>>>(cnt, dinv);

  // weight splits (tiny)
  k_splitw<<<(128 * 256 + 255) / 256, 256, 0, stream>>>(W2, W2hi, W2lo, 128, 256);
  k_splitw<<<(256 * 256 + 255) / 256, 256, 0, stream>>>(W3, W3hi, W3lo, 256, 256);
  k_splitw<<<(256 * 256 + 255) / 256, 256, 0, stream>>>(W4, W4hi, W4lo, 256, 256);

  // layer 1: agg 9-dim, GEMM 9->128 (+relu), fp32
  k_agg9<<<(NN + 255) / 256, 256, 0, stream>>>(x, agg9out, cnt, col, dinv);
  k_gemm9<<<NN / 2, 256, 0, stream>>>(agg9out, W1, b1, h);

  dim3 gmm((NN + 127) / 128, 2);

  // layer 2: agg 128-dim (split emit), MFMA GEMM 128->256 (+relu)
  k_agg128<<<(NN + 3) / 4, 256, 0, stream>>>((const float2*)h, Ahi, Alo, cnt, col, dinv);
  k_mm<<<gmm, 256, 0, stream>>>(Ahi, Alo, W2hi, W2lo, b2, h, NN, 128, 256, 1);

  // layer 3
  k_agg256<<<(NN + 3) / 4, 256, 0, stream>>>((const float4*)h, Ahi, Alo, cnt, col, dinv);
  k_mm<<<gmm, 256, 0, stream>>>(Ahi, Alo, W3hi, W3lo, b3, h, NN, 256, 256, 1);

  // layer 4 (no relu)
  k_agg256<<<(NN + 3) / 4, 256, 0, stream>>>((const float4*)h, Ahi, Alo, cnt, col, dinv);
  k_mm<<<gmm, 256, 0, stream>>>(Ahi, Alo, W4hi, W4lo, b4, h, NN, 256, 256, 0);

  // pool + head
  k_pool<<<(NN + PCH - 1) / PCH, 256, 0, stream>>>(h, batch, g);
  k_head<<<NG, 256, 0, stream>>>(g, Wl2, bl2, Wl3, bl3, Wl, bl, out);
}

// Round 3
// 713.526 us; speedup vs baseline: 1.1421x; 1.0526x over previous
//
#include <hip/hip_runtime.h>
#include <float.h>

#define NN 50000
#define NE 800000
#define NG 64
#define CAP 64

typedef __attribute__((ext_vector_type(8))) short bf16x8;
typedef __attribute__((ext_vector_type(4))) float f32x4;

// ---------- helpers ----------
__device__ __forceinline__ unsigned f2mono(float f) {
  unsigned b = __float_as_uint(f);
  return (b & 0x80000000u) ? ~b : (b | 0x80000000u);
}
__device__ __forceinline__ float mono2f(unsigned u) {
  unsigned b = (u & 0x80000000u) ? (u & 0x7fffffffu) : ~u;
  return __uint_as_float(b);
}
__device__ __forceinline__ unsigned short bf16rn(float f) {
  unsigned u = __float_as_uint(f);
  unsigned r = u + 0x7FFFu + ((u >> 16) & 1u);
  return (unsigned short)(r >> 16);
}
__device__ __forceinline__ float bf2f(unsigned short h) {
  return __uint_as_float(((unsigned)h) << 16);
}
__device__ __forceinline__ void split2(float a, unsigned short* hi, unsigned short* lo) {
  unsigned short h = bf16rn(a);
  *hi = h;
  *lo = bf16rn(a - bf2f(h));
}

// ---------- degree count + ELL adjacency fill (by dst) ----------
__global__ void k_count(const int* __restrict__ src, const int* __restrict__ dst,
                        int* __restrict__ cnt, int* __restrict__ col) {
  int e = blockIdx.x * blockDim.x + threadIdx.x;
  if (e >= NE) return;
  int d = dst[e];
  int s = src[e];
  if ((unsigned)d >= NN || (unsigned)s >= NN) return;
  int pos = atomicAdd(&cnt[d], 1);
  if (pos < CAP) col[d * CAP + pos] = s;
}

// dinv + pre-scaled input features xs = x * dinv[v]
__global__ void k_dinv(const int* __restrict__ cnt, float* __restrict__ dinv,
                       const float* __restrict__ x, float* __restrict__ xs) {
  int v = blockIdx.x * blockDim.x + threadIdx.x;
  if (v >= NN) return;
  float d = rsqrtf((float)cnt[v] + 1.0f);
  dinv[v] = d;
#pragma unroll
  for (int i = 0; i < 9; ++i) xs[v * 9 + i] = x[v * 9 + i] * d;
}

// ---------- weight split + transpose: W[K][Nc] fp32 -> Wt_hi/lo[Nc][K] bf16 ----------
__global__ void k_splitw(const float* __restrict__ W, unsigned short* __restrict__ Whi,
                         unsigned short* __restrict__ Wlo, int K, int Nc) {
  int i = blockIdx.x * blockDim.x + threadIdx.x;
  if (i >= K * Nc) return;
  int k = i / Nc, n = i - k * Nc;
  float w = W[i];
  unsigned short h, l;
  split2(w, &h, &l);
  Whi[(size_t)n * K + k] = h;
  Wlo[(size_t)n * K + k] = l;
}

// ---------- aggregation F=9: 16-lane group per node, xs pre-scaled ----------
__global__ __launch_bounds__(256) void k_agg9(const float* __restrict__ xs,
                                              float* __restrict__ out,
                                              const int* __restrict__ cnt,
                                              const int* __restrict__ col,
                                              const float* __restrict__ dinv) {
  int v = (blockIdx.x * 256 + threadIdx.x) >> 4;
  int l = threadIdx.x & 15;
  if (v >= NN) return;
  int c = cnt[v]; if (c > CAP) c = CAP;
  const int* cl = col + v * CAP;
  float acc = (l < 9) ? xs[v * 9 + l] : 0.0f;   // self term (pre-scaled)
  int j = 0;
  for (; j + 4 <= c; j += 4) {
    int4 u = *(const int4*)(cl + j);
    float a0 = (l < 9) ? xs[u.x * 9 + l] : 0.f;
    float a1 = (l < 9) ? xs[u.y * 9 + l] : 0.f;
    float a2 = (l < 9) ? xs[u.z * 9 + l] : 0.f;
    float a3 = (l < 9) ? xs[u.w * 9 + l] : 0.f;
    acc += (a0 + a1) + (a2 + a3);
  }
  for (; j < c; ++j) {
    int u = cl[j];
    if (l < 9) acc += xs[u * 9 + l];
  }
  if (l < 9) out[v * 9 + l] = acc * dinv[v];
}

// ---------- GEMM K=9 -> 128, + bias + relu, epilogue scales by dinv ----------
__global__ __launch_bounds__(256) void k_gemm9(const float* __restrict__ in,
                                               const float* __restrict__ W,
                                               const float* __restrict__ bias,
                                               const float* __restrict__ dinv,
                                               float* __restrict__ out) {
  __shared__ float sW[9 * 128];
  __shared__ float sb[128];
  int t = threadIdx.x;
  if (t < 128) sb[t] = bias[t];
  for (int i = t; i < 9 * 128; i += 256) sW[i] = W[i];
  __syncthreads();
  int r = blockIdx.x * 2 + (t >> 7);
  int c = t & 127;
  if (r >= NN) return;
  float acc = sb[c];
#pragma unroll
  for (int i = 0; i < 9; ++i) acc += in[r * 9 + i] * sW[i * 128 + c];
  out[r * 128 + c] = fmaxf(acc, 0.0f) * dinv[r];   // pre-scaled for next agg
}

// ---------- aggregation F=128 (wave/node, unroll 4), h pre-scaled, emits split bf16 ----------
__global__ __launch_bounds__(256) void k_agg128(const float2* __restrict__ h,
                                                unsigned short* __restrict__ Ahi,
                                                unsigned short* __restrict__ Alo,
                                                const int* __restrict__ cnt,
                                                const int* __restrict__ col,
                                                const float* __restrict__ dinv) {
  int w = (blockIdx.x * 256 + threadIdx.x) >> 6;
  int lane = threadIdx.x & 63;
  if (w >= NN) return;
  float2 s = h[(size_t)w * 64 + lane];
  float ax = s.x, ay = s.y;                       // self (pre-scaled)
  int c = cnt[w]; if (c > CAP) c = CAP;
  const int* cl = col + w * CAP;
  int j = 0;
  for (; j + 4 <= c; j += 4) {
    int4 u = *(const int4*)(cl + j);
    float2 t0 = h[(size_t)u.x * 64 + lane];
    float2 t1 = h[(size_t)u.y * 64 + lane];
    float2 t2 = h[(size_t)u.z * 64 + lane];
    float2 t3 = h[(size_t)u.w * 64 + lane];
    ax += (t0.x + t1.x) + (t2.x + t3.x);
    ay += (t0.y + t1.y) + (t2.y + t3.y);
  }
  for (; j < c; ++j) {
    int u = cl[j];
    float2 tv = h[(size_t)u * 64 + lane];
    ax += tv.x; ay += tv.y;
  }
  float di = dinv[w];
  ax *= di; ay *= di;
  ushort2 hv, lv;
  split2(ax, &hv.x, &lv.x);
  split2(ay, &hv.y, &lv.y);
  *(ushort2*)(Ahi + (size_t)w * 128 + 2 * lane) = hv;
  *(ushort2*)(Alo + (size_t)w * 128 + 2 * lane) = lv;
}

// ---------- aggregation F=256 (wave/node, unroll 4), h pre-scaled, emits split bf16 ----------
__global__ __launch_bounds__(256) void k_agg256(const float4* __restrict__ h,
                                                unsigned short* __restrict__ Ahi,
                                                unsigned short* __restrict__ Alo,
                                                const int* __restrict__ cnt,
                                                const int* __restrict__ col,
                                                const float* __restrict__ dinv) {
  int w = (blockIdx.x * 256 + threadIdx.x) >> 6;
  int lane = threadIdx.x & 63;
  if (w >= NN) return;
  float4 s = h[(size_t)w * 64 + lane];
  float ax = s.x, ay = s.y, az = s.z, aw = s.w;   // self (pre-scaled)
  int c = cnt[w]; if (c > CAP) c = CAP;
  const int* cl = col + w * CAP;
  int j = 0;
  for (; j + 4 <= c; j += 4) {
    int4 u = *(const int4*)(cl + j);
    float4 t0 = h[(size_t)u.x * 64 + lane];
    float4 t1 = h[(size_t)u.y * 64 + lane];
    float4 t2 = h[(size_t)u.z * 64 + lane];
    float4 t3 = h[(size_t)u.w * 64 + lane];
    ax += (t0.x + t1.x) + (t2.x + t3.x);
    ay += (t0.y + t1.y) + (t2.y + t3.y);
    az += (t0.z + t1.z) + (t2.z + t3.z);
    aw += (t0.w + t1.w) + (t2.w + t3.w);
  }
  for (; j < c; ++j) {
    int u = cl[j];
    float4 tv = h[(size_t)u * 64 + lane];
    ax += tv.x; ay += tv.y; az += tv.z; aw += tv.w;
  }
  float di = dinv[w];
  ax *= di; ay *= di; az *= di; aw *= di;
  ushort4 hv, lv;
  split2(ax, &hv.x, &lv.x);
  split2(ay, &hv.y, &lv.y);
  split2(az, &hv.z, &lv.z);
  split2(aw, &hv.w, &lv.w);
  *(ushort4*)(Ahi + (size_t)w * 256 + 4 * lane) = hv;
  *(ushort4*)(Alo + (size_t)w * 256 + 4 * lane) = lv;
}

// ---------- MFMA bf16x3-split GEMM ----------
// mode 1: C = relu(acc+bias) * dinv[row]  (feeds next aggregation)
// mode 2: no C write; per-block LDS max-pool then global atomicMax into gpool
__global__ __launch_bounds__(256) void k_mm(const unsigned short* __restrict__ Ahi,
                                            const unsigned short* __restrict__ Alo,
                                            const unsigned short* __restrict__ Bhi,
                                            const unsigned short* __restrict__ Blo,
                                            const float* __restrict__ bias,
                                            float* __restrict__ C,
                                            const float* __restrict__ dinv,
                                            const int* __restrict__ batch,
                                            unsigned* __restrict__ gpool,
                                            int M, int K, int Nc, int mode) {
  __shared__ unsigned ldsPool[4 * 256];
  int t = threadIdx.x;
  if (mode == 2) {
    for (int i = t; i < 4 * 256; i += 256) ldsPool[i] = 0u;
    __syncthreads();
  }
  int wave = t >> 6, lane = t & 63;
  int wm = wave & 1, wn = wave >> 1;
  int rowBase = blockIdx.x * 128 + wm * 64;
  int colBase = blockIdx.y * 128 + wn * 64;
  int lm = lane & 15;
  int lk = (lane >> 4) * 8;

  f32x4 acc[4][4];
#pragma unroll
  for (int i = 0; i < 4; ++i)
#pragma unroll
    for (int j = 0; j < 4; ++j) acc[i][j] = (f32x4){0.f, 0.f, 0.f, 0.f};

  const bf16x8 zf = {};

  for (int k0 = 0; k0 < K; k0 += 32) {
    bf16x8 ah[4], al[4], bh[4], bl[4];
#pragma unroll
    for (int mi = 0; mi < 4; ++mi) {
      int r = rowBase + mi * 16 + lm;
      if (r < M) {
        size_t off = (size_t)r * K + k0 + lk;
        ah[mi] = *(const bf16x8*)(Ahi + off);
        al[mi] = *(const bf16x8*)(Alo + off);
      } else { ah[mi] = zf; al[mi] = zf; }
    }
#pragma unroll
    for (int ni = 0; ni < 4; ++ni) {
      int c = colBase + ni * 16 + lm;
      size_t off = (size_t)c * K + k0 + lk;
      bh[ni] = *(const bf16x8*)(Bhi + off);
      bl[ni] = *(const bf16x8*)(Blo + off);
    }
#pragma unroll
    for (int mi = 0; mi < 4; ++mi)
#pragma unroll
      for (int ni = 0; ni < 4; ++ni) {
        acc[mi][ni] = __builtin_amdgcn_mfma_f32_16x16x32_bf16(ah[mi], bh[ni], acc[mi][ni], 0, 0, 0);
        acc[mi][ni] = __builtin_amdgcn_mfma_f32_16x16x32_bf16(ah[mi], bl[ni], acc[mi][ni], 0, 0, 0);
        acc[mi][ni] = __builtin_amdgcn_mfma_f32_16x16x32_bf16(al[mi], bh[ni], acc[mi][ni], 0, 0, 0);
      }
  }

  // C/D layout: col = lane&15, row = (lane>>4)*4 + reg
  int rowOff = (lane >> 4) * 4;
  if (mode == 2) {
    int b0 = batch[blockIdx.x * 128];
#pragma unroll
    for (int mi = 0; mi < 4; ++mi) {
#pragma unroll
      for (int ni = 0; ni < 4; ++ni) {
        int gc = colBase + ni * 16 + lm;
        float bsv = bias[gc];
#pragma unroll
        for (int r = 0; r < 4; ++r) {
          int gr = rowBase + mi * 16 + rowOff + r;
          if (gr < M) {
            float v = acc[mi][ni][r] + bsv;
            int idx = batch[gr] - b0;
            if (idx < 0) idx = 0;
            if (idx > 3) idx = 3;
            atomicMax(&ldsPool[idx * 256 + gc], f2mono(v));
          }
        }
      }
    }
    __syncthreads();
#pragma unroll
    for (int s = 0; s < 4; ++s) {
      unsigned mv = ldsPool[s * 256 + t];
      int gb = b0 + s;
      if (mv && gb < NG) atomicMax(&gpool[gb * 256 + t], mv);
    }
  } else {
#pragma unroll
    for (int mi = 0; mi < 4; ++mi) {
#pragma unroll
      for (int ni = 0; ni < 4; ++ni) {
        int gc = colBase + ni * 16 + lm;
        float bsv = bias[gc];
#pragma unroll
        for (int r = 0; r < 4; ++r) {
          int gr = rowBase + mi * 16 + rowOff + r;
          if (gr < M) {
            float v = fmaxf(acc[mi][ni][r] + bsv, 0.0f);
            C[(size_t)gr * Nc + gc] = v * dinv[gr];   // pre-scaled for next agg
          }
        }
      }
    }
  }
}

// ---------- dense head ----------
__global__ __launch_bounds__(256) void k_head(const unsigned* __restrict__ g,
                                              const float* __restrict__ Wl2, const float* __restrict__ bl2,
                                              const float* __restrict__ Wl3, const float* __restrict__ bl3,
                                              const float* __restrict__ Wl, const float* __restrict__ bl,
                                              float* __restrict__ out) {
  __shared__ float s0[256];
  __shared__ float s1[128];
  __shared__ float s2[128];
  int b = blockIdx.x, t = threadIdx.x;
  s0[t] = mono2f(g[b * 256 + t]);
  __syncthreads();
  if (t < 128) {
    float acc = bl2[t];
    for (int k = 0; k < 256; ++k) acc += s0[k] * Wl2[k * 128 + t];
    s1[t] = fmaxf(acc, 0.0f);
  }
  __syncthreads();
  if (t < 128) {
    float acc = bl3[t];
    for (int k = 0; k < 128; ++k) acc += s1[k] * Wl3[k * 128 + t];
    s2[t] = fmaxf(acc, 0.0f);
  }
  __syncthreads();
  if (t < 10) {
    float acc = bl[t];
    for (int k = 0; k < 128; ++k) acc += s2[k] * Wl[k * 10 + t];
    out[b * 10 + t] = acc;
  }
}

extern "C" void kernel_launch(void* const* d_in, const int* in_sizes, int n_in,
                              void* d_out, int out_size, void* d_ws, size_t ws_size,
                              hipStream_t stream) {
  const float* x   = (const float*)d_in[0];
  const int* eidx  = (const int*)d_in[1];
  const int* batch = (const int*)d_in[2];
  const float* W1 = (const float*)d_in[3];   const float* b1 = (const float*)d_in[4];
  const float* W2 = (const float*)d_in[5];   const float* b2 = (const float*)d_in[6];
  const float* W3 = (const float*)d_in[7];   const float* b3 = (const float*)d_in[8];
  const float* W4 = (const float*)d_in[9];   const float* b4 = (const float*)d_in[10];
  const float* Wl2 = (const float*)d_in[11]; const float* bl2 = (const float*)d_in[12];
  const float* Wl3 = (const float*)d_in[13]; const float* bl3 = (const float*)d_in[14];
  const float* Wl  = (const float*)d_in[15]; const float* bl  = (const float*)d_in[16];
  float* out = (float*)d_out;

  // ---- workspace carve ----
  float* h = (float*)d_ws;                                         // NN*256 fp32
  unsigned short* Ahi = (unsigned short*)(h + (size_t)NN * 256);   // NN*256 bf16
  unsigned short* Alo = Ahi + (size_t)NN * 256;                    // NN*256 bf16
  int* cnt  = (int*)(Alo + (size_t)NN * 256);                      // NN
  float* dinv = (float*)(cnt + NN);                                // NN
  int* col  = (int*)(dinv + NN);                                   // NN*CAP
  unsigned* g = (unsigned*)(col + (size_t)NN * CAP);               // NG*256
  unsigned short* W2hi = (unsigned short*)(g + NG * 256);
  unsigned short* W2lo = W2hi + 128 * 256;
  unsigned short* W3hi = W2lo + 128 * 256;
  unsigned short* W3lo = W3hi + 256 * 256;
  unsigned short* W4hi = W3lo + 256 * 256;
  unsigned short* W4lo = W4hi + 256 * 256;
  float* xs = h;                 // NN*9 fp32, dead before k_gemm9 writes h
  float* agg9out = (float*)Ahi;  // NN*9 fp32, dead before k_agg128 writes Ahi

  const int* src = eidx;
  const int* dst = eidx + NE;

  hipMemsetAsync(cnt, 0, NN * sizeof(int), stream);
  hipMemsetAsync(g, 0, NG * 256 * sizeof(unsigned), stream);

  k_count<<<(NE + 255) / 256, 256, 0, stream>>>(src, dst, cnt, col);
  k_dinv<<<(NN + 255) / 256, 256, 0, stream>>>(cnt, dinv, x, xs);

  k_splitw<<<(128 * 256 + 255) / 256, 256, 0, stream>>>(W2, W2hi, W2lo, 128, 256);
  k_splitw<<<(256 * 256 + 255) / 256, 256, 0, stream>>>(W3, W3hi, W3lo, 256, 256);
  k_splitw<<<(256 * 256 + 255) / 256, 256, 0, stream>>>(W4, W4hi, W4lo, 256, 256);

  // layer 1: agg 9-dim (pre-scaled), GEMM 9->128 (+relu, *dinv)
  k_agg9<<<(NN + 15) / 16, 256, 0, stream>>>(xs, agg9out, cnt, col, dinv);
  k_gemm9<<<NN / 2, 256, 0, stream>>>(agg9out, W1, b1, dinv, h);

  dim3 gmm((NN + 127) / 128, 2);

  // layer 2
  k_agg128<<<(NN + 3) / 4, 256, 0, stream>>>((const float2*)h, Ahi, Alo, cnt, col, dinv);
  k_mm<<<gmm, 256, 0, stream>>>(Ahi, Alo, W2hi, W2lo, b2, h, dinv, batch, g, NN, 128, 256, 1);

  // layer 3
  k_agg256<<<(NN + 3) / 4, 256, 0, stream>>>((const float4*)h, Ahi, Alo, cnt, col, dinv);
  k_mm<<<gmm, 256, 0, stream>>>(Ahi, Alo, W3hi, W3lo, b3, h, dinv, batch, g, NN, 256, 256, 1);

  // layer 4: GEMM + fused max-pool (no C write)
  k_agg256<<<(NN + 3) / 4, 256, 0, stream>>>((const float4*)h, Ahi, Alo, cnt, col, dinv);
  k_mm<<<gmm, 256, 0, stream>>>(Ahi, Alo, W4hi, W4lo, b4, h, dinv, batch, g, NN, 256, 256, 2);

  // head
  k_head<<<NG, 256, 0, stream>>>(g, Wl2, bl2, Wl3, bl3, Wl, bl, out);
}

// Round 4
// 570.353 us; speedup vs baseline: 1.4289x; 1.2510x over previous
//
#include <hip/hip_runtime.h>
#include <float.h>

#define NN 50000
#define NE 800000
#define NG 64
#define CAP 64

typedef __attribute__((ext_vector_type(8))) short bf16x8;
typedef __attribute__((ext_vector_type(4))) float f32x4;
typedef __attribute__((ext_vector_type(4))) _Float16 half4;
typedef __attribute__((ext_vector_type(2))) _Float16 half2v;

// ---------- helpers ----------
__device__ __forceinline__ unsigned f2mono(float f) {
  unsigned b = __float_as_uint(f);
  return (b & 0x80000000u) ? ~b : (b | 0x80000000u);
}
__device__ __forceinline__ float mono2f(unsigned u) {
  unsigned b = (u & 0x80000000u) ? (u & 0x7fffffffu) : ~u;
  return __uint_as_float(b);
}
__device__ __forceinline__ unsigned short bf16rn(float f) {
  unsigned u = __float_as_uint(f);
  unsigned r = u + 0x7FFFu + ((u >> 16) & 1u);
  return (unsigned short)(r >> 16);
}
__device__ __forceinline__ float bf2f(unsigned short h) {
  return __uint_as_float(((unsigned)h) << 16);
}
__device__ __forceinline__ void split2(float a, unsigned short* hi, unsigned short* lo) {
  unsigned short h = bf16rn(a);
  *hi = h;
  *lo = bf16rn(a - bf2f(h));
}

// ---------- degree count + ELL adjacency fill (by dst) ----------
__global__ void k_count(const int* __restrict__ src, const int* __restrict__ dst,
                        int* __restrict__ cnt, int* __restrict__ col) {
  int e = blockIdx.x * blockDim.x + threadIdx.x;
  if (e >= NE) return;
  int d = dst[e];
  int s = src[e];
  if ((unsigned)d >= NN || (unsigned)s >= NN) return;
  int pos = atomicAdd(&cnt[d], 1);
  if (pos < CAP) col[d * CAP + pos] = s;
}

// dinv + pre-scaled input features xs = x * dinv[v] (fp32; layer-1 gather stays fp32)
__global__ void k_dinv(const int* __restrict__ cnt, float* __restrict__ dinv,
                       const float* __restrict__ x, float* __restrict__ xs) {
  int v = blockIdx.x * blockDim.x + threadIdx.x;
  if (v >= NN) return;
  float d = rsqrtf((float)cnt[v] + 1.0f);
  dinv[v] = d;
#pragma unroll
  for (int i = 0; i < 9; ++i) xs[v * 9 + i] = x[v * 9 + i] * d;
}

// ---------- weight split + transpose: W[K][Nc] fp32 -> Wt_hi/lo[Nc][K] bf16 ----------
__global__ void k_splitw(const float* __restrict__ W, unsigned short* __restrict__ Whi,
                         unsigned short* __restrict__ Wlo, int K, int Nc) {
  int i = blockIdx.x * blockDim.x + threadIdx.x;
  if (i >= K * Nc) return;
  int k = i / Nc, n = i - k * Nc;
  float w = W[i];
  unsigned short h, l;
  split2(w, &h, &l);
  Whi[(size_t)n * K + k] = h;
  Wlo[(size_t)n * K + k] = l;
}

// ---------- aggregation F=9: 16-lane group per node, xs pre-scaled fp32 ----------
__global__ __launch_bounds__(256) void k_agg9(const float* __restrict__ xs,
                                              float* __restrict__ out,
                                              const int* __restrict__ cnt,
                                              const int* __restrict__ col,
                                              const float* __restrict__ dinv) {
  int v = (blockIdx.x * 256 + threadIdx.x) >> 4;
  int l = threadIdx.x & 15;
  if (v >= NN) return;
  int c = cnt[v]; if (c > CAP) c = CAP;
  const int* cl = col + v * CAP;
  float acc = (l < 9) ? xs[v * 9 + l] : 0.0f;
  int j = 0;
  for (; j + 4 <= c; j += 4) {
    int4 u = *(const int4*)(cl + j);
    float a0 = (l < 9) ? xs[u.x * 9 + l] : 0.f;
    float a1 = (l < 9) ? xs[u.y * 9 + l] : 0.f;
    float a2 = (l < 9) ? xs[u.z * 9 + l] : 0.f;
    float a3 = (l < 9) ? xs[u.w * 9 + l] : 0.f;
    acc += (a0 + a1) + (a2 + a3);
  }
  for (; j < c; ++j) {
    int u = cl[j];
    if (l < 9) acc += xs[u * 9 + l];
  }
  if (l < 9) out[v * 9 + l] = acc * dinv[v];
}

// ---------- GEMM K=9 -> 128, + bias + relu; writes fp16 (pre-scaled by dinv) ----------
__global__ __launch_bounds__(256) void k_gemm9(const float* __restrict__ in,
                                               const float* __restrict__ W,
                                               const float* __restrict__ bias,
                                               const float* __restrict__ dinv,
                                               _Float16* __restrict__ out) {
  __shared__ float sW[9 * 128];
  __shared__ float sb[128];
  int t = threadIdx.x;
  if (t < 128) sb[t] = bias[t];
  for (int i = t; i < 9 * 128; i += 256) sW[i] = W[i];
  __syncthreads();
  int r = blockIdx.x * 2 + (t >> 7);
  int c = t & 127;
  if (r >= NN) return;
  float acc = sb[c];
#pragma unroll
  for (int i = 0; i < 9; ++i) acc += in[r * 9 + i] * sW[i * 128 + c];
  out[r * 128 + c] = (_Float16)(fmaxf(acc, 0.0f) * dinv[r]);
}

// ---------- aggregation F=128 (wave/node), fp16 gather, emits split bf16 ----------
__global__ __launch_bounds__(256) void k_agg128(const half2v* __restrict__ h,
                                                unsigned short* __restrict__ Ahi,
                                                unsigned short* __restrict__ Alo,
                                                const int* __restrict__ cnt,
                                                const int* __restrict__ col,
                                                const float* __restrict__ dinv) {
  int w = (blockIdx.x * 256 + threadIdx.x) >> 6;
  int lane = threadIdx.x & 63;
  if (w >= NN) return;
  half2v s = h[(size_t)w * 64 + lane];
  float ax = (float)s.x, ay = (float)s.y;
  int c = cnt[w]; if (c > CAP) c = CAP;
  const int* cl = col + w * CAP;
  int j = 0;
  for (; j + 4 <= c; j += 4) {
    int4 u = *(const int4*)(cl + j);
    half2v t0 = h[(size_t)u.x * 64 + lane];
    half2v t1 = h[(size_t)u.y * 64 + lane];
    half2v t2 = h[(size_t)u.z * 64 + lane];
    half2v t3 = h[(size_t)u.w * 64 + lane];
    ax += ((float)t0.x + (float)t1.x) + ((float)t2.x + (float)t3.x);
    ay += ((float)t0.y + (float)t1.y) + ((float)t2.y + (float)t3.y);
  }
  for (; j < c; ++j) {
    int u = cl[j];
    half2v tv = h[(size_t)u * 64 + lane];
    ax += (float)tv.x; ay += (float)tv.y;
  }
  float di = dinv[w];
  ax *= di; ay *= di;
  ushort2 hv, lv;
  split2(ax, &hv.x, &lv.x);
  split2(ay, &hv.y, &lv.y);
  *(ushort2*)(Ahi + (size_t)w * 128 + 2 * lane) = hv;
  *(ushort2*)(Alo + (size_t)w * 128 + 2 * lane) = lv;
}

// ---------- aggregation F=256 (wave/node), fp16 gather, emits split bf16 ----------
__global__ __launch_bounds__(256) void k_agg256(const half4* __restrict__ h,
                                                unsigned short* __restrict__ Ahi,
                                                unsigned short* __restrict__ Alo,
                                                const int* __restrict__ cnt,
                                                const int* __restrict__ col,
                                                const float* __restrict__ dinv) {
  int w = (blockIdx.x * 256 + threadIdx.x) >> 6;
  int lane = threadIdx.x & 63;
  if (w >= NN) return;
  half4 s = h[(size_t)w * 64 + lane];
  float ax = (float)s.x, ay = (float)s.y, az = (float)s.z, aw = (float)s.w;
  int c = cnt[w]; if (c > CAP) c = CAP;
  const int* cl = col + w * CAP;
  int j = 0;
  for (; j + 4 <= c; j += 4) {
    int4 u = *(const int4*)(cl + j);
    half4 t0 = h[(size_t)u.x * 64 + lane];
    half4 t1 = h[(size_t)u.y * 64 + lane];
    half4 t2 = h[(size_t)u.z * 64 + lane];
    half4 t3 = h[(size_t)u.w * 64 + lane];
    ax += ((float)t0.x + (float)t1.x) + ((float)t2.x + (float)t3.x);
    ay += ((float)t0.y + (float)t1.y) + ((float)t2.y + (float)t3.y);
    az += ((float)t0.z + (float)t1.z) + ((float)t2.z + (float)t3.z);
    aw += ((float)t0.w + (float)t1.w) + ((float)t2.w + (float)t3.w);
  }
  for (; j < c; ++j) {
    int u = cl[j];
    half4 tv = h[(size_t)u * 64 + lane];
    ax += (float)tv.x; ay += (float)tv.y; az += (float)tv.z; aw += (float)tv.w;
  }
  float di = dinv[w];
  ax *= di; ay *= di; az *= di; aw *= di;
  ushort4 hv, lv;
  split2(ax, &hv.x, &lv.x);
  split2(ay, &hv.y, &lv.y);
  split2(az, &hv.z, &lv.z);
  split2(aw, &hv.w, &lv.w);
  *(ushort4*)(Ahi + (size_t)w * 256 + 4 * lane) = hv;
  *(ushort4*)(Alo + (size_t)w * 256 + 4 * lane) = lv;
}

// ---------- MFMA bf16x3-split GEMM ----------
// mode 1: C(fp16) = relu(acc+bias) * dinv[row]  (feeds next fp16 gather)
// mode 2: no C write; per-block LDS max-pool (fp32 path) then global atomicMax
__global__ __launch_bounds__(256) void k_mm(const unsigned short* __restrict__ Ahi,
                                            const unsigned short* __restrict__ Alo,
                                            const unsigned short* __restrict__ Bhi,
                                            const unsigned short* __restrict__ Blo,
                                            const float* __restrict__ bias,
                                            _Float16* __restrict__ C,
                                            const float* __restrict__ dinv,
                                            const int* __restrict__ batch,
                                            unsigned* __restrict__ gpool,
                                            int M, int K, int Nc, int mode) {
  __shared__ unsigned ldsPool[4 * 256];
  int t = threadIdx.x;
  if (mode == 2) {
    for (int i = t; i < 4 * 256; i += 256) ldsPool[i] = 0u;
    __syncthreads();
  }
  int wave = t >> 6, lane = t & 63;
  int wm = wave & 1, wn = wave >> 1;
  int rowBase = blockIdx.x * 128 + wm * 64;
  int colBase = blockIdx.y * 128 + wn * 64;
  int lm = lane & 15;
  int lk = (lane >> 4) * 8;

  f32x4 acc[4][4];
#pragma unroll
  for (int i = 0; i < 4; ++i)
#pragma unroll
    for (int j = 0; j < 4; ++j) acc[i][j] = (f32x4){0.f, 0.f, 0.f, 0.f};

  const bf16x8 zf = {};

  for (int k0 = 0; k0 < K; k0 += 32) {
    bf16x8 ah[4], al[4], bh[4], bl[4];
#pragma unroll
    for (int mi = 0; mi < 4; ++mi) {
      int r = rowBase + mi * 16 + lm;
      if (r < M) {
        size_t off = (size_t)r * K + k0 + lk;
        ah[mi] = *(const bf16x8*)(Ahi + off);
        al[mi] = *(const bf16x8*)(Alo + off);
      } else { ah[mi] = zf; al[mi] = zf; }
    }
#pragma unroll
    for (int ni = 0; ni < 4; ++ni) {
      int c = colBase + ni * 16 + lm;
      size_t off = (size_t)c * K + k0 + lk;
      bh[ni] = *(const bf16x8*)(Bhi + off);
      bl[ni] = *(const bf16x8*)(Blo + off);
    }
#pragma unroll
    for (int mi = 0; mi < 4; ++mi)
#pragma unroll
      for (int ni = 0; ni < 4; ++ni) {
        acc[mi][ni] = __builtin_amdgcn_mfma_f32_16x16x32_bf16(ah[mi], bh[ni], acc[mi][ni], 0, 0, 0);
        acc[mi][ni] = __builtin_amdgcn_mfma_f32_16x16x32_bf16(ah[mi], bl[ni], acc[mi][ni], 0, 0, 0);
        acc[mi][ni] = __builtin_amdgcn_mfma_f32_16x16x32_bf16(al[mi], bh[ni], acc[mi][ni], 0, 0, 0);
      }
  }

  // C/D layout: col = lane&15, row = (lane>>4)*4 + reg
  int rowOff = (lane >> 4) * 4;
  if (mode == 2) {
    int b0 = batch[blockIdx.x * 128];
#pragma unroll
    for (int mi = 0; mi < 4; ++mi) {
#pragma unroll
      for (int ni = 0; ni < 4; ++ni) {
        int gc = colBase + ni * 16 + lm;
        float bsv = bias[gc];
#pragma unroll
        for (int r = 0; r < 4; ++r) {
          int gr = rowBase + mi * 16 + rowOff + r;
          if (gr < M) {
            float v = acc[mi][ni][r] + bsv;
            int idx = batch[gr] - b0;
            if (idx < 0) idx = 0;
            if (idx > 3) idx = 3;
            atomicMax(&ldsPool[idx * 256 + gc], f2mono(v));
          }
        }
      }
    }
    __syncthreads();
#pragma unroll
    for (int s = 0; s < 4; ++s) {
      unsigned mv = ldsPool[s * 256 + t];
      int gb = b0 + s;
      if (mv && gb < NG) atomicMax(&gpool[gb * 256 + t], mv);
    }
  } else {
#pragma unroll
    for (int mi = 0; mi < 4; ++mi) {
#pragma unroll
      for (int ni = 0; ni < 4; ++ni) {
        int gc = colBase + ni * 16 + lm;
        float bsv = bias[gc];
#pragma unroll
        for (int r = 0; r < 4; ++r) {
          int gr = rowBase + mi * 16 + rowOff + r;
          if (gr < M) {
            float v = fmaxf(acc[mi][ni][r] + bsv, 0.0f);
            C[(size_t)gr * Nc + gc] = (_Float16)(v * dinv[gr]);
          }
        }
      }
    }
  }
}

// ---------- dense head ----------
__global__ __launch_bounds__(256) void k_head(const unsigned* __restrict__ g,
                                              const float* __restrict__ Wl2, const float* __restrict__ bl2,
                                              const float* __restrict__ Wl3, const float* __restrict__ bl3,
                                              const float* __restrict__ Wl, const float* __restrict__ bl,
                                              float* __restrict__ out) {
  __shared__ float s0[256];
  __shared__ float s1[128];
  __shared__ float s2[128];
  int b = blockIdx.x, t = threadIdx.x;
  s0[t] = mono2f(g[b * 256 + t]);
  __syncthreads();
  if (t < 128) {
    float acc = bl2[t];
    for (int k = 0; k < 256; ++k) acc += s0[k] * Wl2[k * 128 + t];
    s1[t] = fmaxf(acc, 0.0f);
  }
  __syncthreads();
  if (t < 128) {
    float acc = bl3[t];
    for (int k = 0; k < 128; ++k) acc += s1[k] * Wl3[k * 128 + t];
    s2[t] = fmaxf(acc, 0.0f);
  }
  __syncthreads();
  if (t < 10) {
    float acc = bl[t];
    for (int k = 0; k < 128; ++k) acc += s2[k] * Wl[k * 10 + t];
    out[b * 10 + t] = acc;
  }
}

extern "C" void kernel_launch(void* const* d_in, const int* in_sizes, int n_in,
                              void* d_out, int out_size, void* d_ws, size_t ws_size,
                              hipStream_t stream) {
  const float* x   = (const float*)d_in[0];
  const int* eidx  = (const int*)d_in[1];
  const int* batch = (const int*)d_in[2];
  const float* W1 = (const float*)d_in[3];   const float* b1 = (const float*)d_in[4];
  const float* W2 = (const float*)d_in[5];   const float* b2 = (const float*)d_in[6];
  const float* W3 = (const float*)d_in[7];   const float* b3 = (const float*)d_in[8];
  const float* W4 = (const float*)d_in[9];   const float* b4 = (const float*)d_in[10];
  const float* Wl2 = (const float*)d_in[11]; const float* bl2 = (const float*)d_in[12];
  const float* Wl3 = (const float*)d_in[13]; const float* bl3 = (const float*)d_in[14];
  const float* Wl  = (const float*)d_in[15]; const float* bl  = (const float*)d_in[16];
  float* out = (float*)d_out;

  // ---- workspace carve ----
  _Float16* hs = (_Float16*)d_ws;                                  // NN*256 fp16
  unsigned short* Ahi = (unsigned short*)(hs + (size_t)NN * 256);  // NN*256 bf16
  unsigned short* Alo = Ahi + (size_t)NN * 256;                    // NN*256 bf16
  int* cnt  = (int*)(Alo + (size_t)NN * 256);                      // NN
  float* dinv = (float*)(cnt + NN);                                // NN
  int* col  = (int*)(dinv + NN);                                   // NN*CAP
  unsigned* g = (unsigned*)(col + (size_t)NN * CAP);               // NG*256
  unsigned short* W2hi = (unsigned short*)(g + NG * 256);
  unsigned short* W2lo = W2hi + 128 * 256;
  unsigned short* W3hi = W2lo + 128 * 256;
  unsigned short* W3lo = W3hi + 256 * 256;
  unsigned short* W4hi = W3lo + 256 * 256;
  unsigned short* W4lo = W4hi + 256 * 256;
  float* xs = (float*)hs;        // NN*9 fp32, dead before k_gemm9 writes hs
  float* agg9out = (float*)Ahi;  // NN*9 fp32, dead before k_agg128 writes Ahi

  const int* src = eidx;
  const int* dst = eidx + NE;

  hipMemsetAsync(cnt, 0, NN * sizeof(int), stream);
  hipMemsetAsync(g, 0, NG * 256 * sizeof(unsigned), stream);

  k_count<<<(NE + 255) / 256, 256, 0, stream>>>(src, dst, cnt, col);
  k_dinv<<<(NN + 255) / 256, 256, 0, stream>>>(cnt, dinv, x, xs);

  k_splitw<<<(128 * 256 + 255) / 256, 256, 0, stream>>>(W2, W2hi, W2lo, 128, 256);
  k_splitw<<<(256 * 256 + 255) / 256, 256, 0, stream>>>(W3, W3hi, W3lo, 256, 256);
  k_splitw<<<(256 * 256 + 255) / 256, 256, 0, stream>>>(W4, W4hi, W4lo, 256, 256);

  // layer 1: agg 9-dim fp32, GEMM 9->128 (+relu, *dinv, fp16 out)
  k_agg9<<<(NN + 15) / 16, 256, 0, stream>>>(xs, agg9out, cnt, col, dinv);
  k_gemm9<<<NN / 2, 256, 0, stream>>>(agg9out, W1, b1, dinv, hs);

  dim3 gmm((NN + 127) / 128, 2);

  // layer 2: fp16 gather 128-dim, MFMA GEMM 128->256
  k_agg128<<<(NN + 3) / 4, 256, 0, stream>>>((const half2v*)hs, Ahi, Alo, cnt, col, dinv);
  k_mm<<<gmm, 256, 0, stream>>>(Ahi, Alo, W2hi, W2lo, b2, hs, dinv, batch, g, NN, 128, 256, 1);

  // layer 3: fp16 gather 256-dim
  k_agg256<<<(NN + 3) / 4, 256, 0, stream>>>((const half4*)hs, Ahi, Alo, cnt, col, dinv);
  k_mm<<<gmm, 256, 0, stream>>>(Ahi, Alo, W3hi, W3lo, b3, hs, dinv, batch, g, NN, 256, 256, 1);

  // layer 4: fp16 gather 256-dim, GEMM + fused max-pool (no C write)
  k_agg256<<<(NN + 3) / 4, 256, 0, stream>>>((const half4*)hs, Ahi, Alo, cnt, col, dinv);
  k_mm<<<gmm, 256, 0, stream>>>(Ahi, Alo, W4hi, W4lo, b4, hs, dinv, batch, g, NN, 256, 256, 2);

  // head
  k_head<<<NG, 256, 0, stream>>>(g, Wl2, bl2, Wl3, bl3, Wl, bl, out);
}